// Round 5
// baseline (1812.986 us; speedup 1.0000x reference)
//
#include <hip/hip_runtime.h>
#include <hip/hip_bf16.h>
#include <stdint.h>

#define N_IN 250000
#define N_OUT 500000
#define INC 256
#define OUTC 128
#define KVOL 8
#define NTOT (KVOL * N_IN)   // 2,000,000 contributions
#define BN_EPS 1e-5f
#define DCHUNKS 489          // ceil(N_OUT / 1024)

typedef __bf16 bf16x8_t __attribute__((ext_vector_type(8)));
typedef __bf16 bf16x4_t __attribute__((ext_vector_type(4)));
typedef float f32x4_t __attribute__((ext_vector_type(4)));

__device__ __forceinline__ __bf16 f2bf(float x) {
  union { float f; uint32_t u; } v; v.f = x;
  uint32_t r = v.u + 0x7FFFu + ((v.u >> 16) & 1u);
  union { uint16_t s; __bf16 b; } o; o.s = (uint16_t)(r >> 16);
  return o.b;
}

__device__ __forceinline__ uint32_t pack2bf(float lo, float hi) {
  union { float f; uint32_t u; } a, b; a.f = lo; b.f = hi;
  uint32_t ra = a.u + 0x7FFFu + ((a.u >> 16) & 1u);
  uint32_t rb = b.u + 0x7FFFu + ((b.u >> 16) & 1u);
  return (ra >> 16) | (rb & 0xFFFF0000u);
}

__device__ __forceinline__ float bflo(uint32_t w) {
  union { uint32_t u; float f; } v; v.u = w << 16; return v.f;
}
__device__ __forceinline__ float bfhi(uint32_t w) {
  union { uint32_t u; float f; } v; v.u = w & 0xFFFF0000u; return v.f;
}

// ======================= conversions =======================

// x[250000][256] f32 -> xb[250000][256] bf16 (8 elems/thread)
__global__ void xconv_kernel(const float* __restrict__ x, uint32_t* __restrict__ xb) {
  int g = blockIdx.x * 256 + threadIdx.x;
  if (g >= N_IN * INC / 8) return;
  const float4* p = (const float4*)x + (size_t)g * 2;
  float4 v0 = p[0], v1 = p[1];
  uint4 o;
  o.x = pack2bf(v0.x, v0.y); o.y = pack2bf(v0.z, v0.w);
  o.z = pack2bf(v1.x, v1.y); o.w = pack2bf(v1.z, v1.w);
  ((uint4*)xb)[g] = o;
}

// W[k][inc][outc] fp32 -> Wt[k][outc][inc] bf16
__global__ void wconv_kernel(const float* __restrict__ W, __bf16* __restrict__ Wt) {
  int f = blockIdx.x * blockDim.x + threadIdx.x;
  if (f >= KVOL * OUTC * INC) return;
  int i = f & (INC - 1);
  int o = (f >> 8) & (OUTC - 1);
  int k = f >> 15;
  Wt[f] = f2bf(W[(k * INC + i) * OUTC + o]);
}

// ======================= counting sort (per-k + global) =======================

// grid (977, 8): per-(k,d) and global-d histograms
__global__ void hist8_kernel(const int* __restrict__ oidx, int* __restrict__ cnt8,
                             int* __restrict__ gcnt) {
  int i = blockIdx.x * 256 + threadIdx.x;
  int k = blockIdx.y;
  if (i < N_IN) {
    int d = oidx[k * N_IN + i];
    atomicAdd(&cnt8[k * N_OUT + d], 1);
    atomicAdd(&gcnt[d], 1);
  }
}

// chunked exclusive scan of one 1024-chunk; grid (DCHUNKS, nstream)
__global__ void scan1s_kernel(const int* __restrict__ in, int* __restrict__ out,
                              int* __restrict__ bsum) {
  __shared__ int sd[256];
  int t = threadIdx.x;
  int s = blockIdx.y;
  const int* inp = in + (size_t)s * N_OUT;
  int* outp = out + (size_t)s * N_OUT;
  int base = blockIdx.x * 1024 + t * 4;
  int v0 = 0, v1 = 0, v2 = 0, v3 = 0;
  if (base + 3 < N_OUT) {
    int4 v = *(const int4*)&inp[base];
    v0 = v.x; v1 = v.y; v2 = v.z; v3 = v.w;
  } else {
    if (base     < N_OUT) v0 = inp[base];
    if (base + 1 < N_OUT) v1 = inp[base + 1];
    if (base + 2 < N_OUT) v2 = inp[base + 2];
  }
  int sm = v0 + v1 + v2 + v3;
  sd[t] = sm; __syncthreads();
  for (int o = 1; o < 256; o <<= 1) {
    int a = (t >= o) ? sd[t - o] : 0;
    __syncthreads();
    sd[t] += a;
    __syncthreads();
  }
  int excl = sd[t] - sm;
  if (base     < N_OUT) outp[base]     = excl;
  if (base + 1 < N_OUT) outp[base + 1] = excl + v0;
  if (base + 2 < N_OUT) outp[base + 2] = excl + v0 + v1;
  if (base + 3 < N_OUT) outp[base + 3] = excl + v0 + v1 + v2;
  if (t == 255) bsum[s * DCHUNKS + blockIdx.x] = sd[255];
}

// per-stream scan of chunk totals; grid (nstream), 512 thr, DCHUNKS<=512
__global__ void scan2s_kernel(const int* __restrict__ bsum, int* __restrict__ bsumx) {
  __shared__ int sd[512];
  int t = threadIdx.x;
  int s = blockIdx.x;
  int v = (t < DCHUNKS) ? bsum[s * DCHUNKS + t] : 0;
  sd[t] = v; __syncthreads();
  for (int o = 1; o < 512; o <<= 1) {
    int a = (t >= o) ? sd[t - o] : 0;
    __syncthreads();
    sd[t] += a;
    __syncthreads();
  }
  if (t < DCHUNKS) bsumx[s * DCHUNKS + t] = sd[t] - v;
}

// finalize per-k cursors; grid (1954, 8)
__global__ void scan3s_kernel(int* __restrict__ cur8, const int* __restrict__ bsumx) {
  int g = blockIdx.x * 256 + threadIdx.x;
  int s = blockIdx.y;
  if (g < N_OUT) cur8[(size_t)s * N_OUT + g] += bsumx[s * DCHUNKS + (g >> 10)];
}

// finalize global offsets: goffs (immutable, for reduce) + gcur (fill cursor)
__global__ void scan3g_kernel(int* __restrict__ goffs, int* __restrict__ gcur,
                              const int* __restrict__ bsumx) {
  int g = blockIdx.x * 256 + threadIdx.x;
  if (g < N_OUT) {
    int v = goffs[g] + bsumx[g >> 10];
    goffs[g] = v;
    gcur[g] = v;
  }
  if (g == 0) goffs[N_OUT] = NTOT;
}

// grid (977, 8): build d-sorted per-k stream (ssrc) + global slot (sgslot)
__global__ void fill_kernel(const int* __restrict__ oidx, int* __restrict__ cur8,
                            int* __restrict__ gcur, int* __restrict__ ssrc,
                            int* __restrict__ sgslot) {
  int i = blockIdx.x * 256 + threadIdx.x;
  int k = blockIdx.y;
  if (i < N_IN) {
    int d = oidx[k * N_IN + i];
    int j = atomicAdd(&cur8[(size_t)k * N_OUT + d], 1);   // stream-local pos
    int g = atomicAdd(&gcur[d], 1);                       // global d-sorted pos
    ssrc[k * N_IN + j] = i;
    sgslot[k * N_IN + j] = g;
  }
}

// ======================= gather-GEMM -> streaming partials =======================

#define GTM 64
#define LDS_STRIDE 264  // bf16 elems per xs row (256 + 8 pad)

// grid (3907, 8); 512 thr = 8 waves. Block = (k = blockIdx.y, 64 d-sorted slots).
// Gathers 64 x_bf16 rows (L3-resident), computes transposed D[chan][voxel] via
// MFMA with shared W[k], writes 256B bf16 partial rows to sgslot positions
// (monotonically increasing => semi-sequential HBM writes).
__global__ __launch_bounds__(512, 1) void gemm_gather_store_kernel(
    const uint32_t* __restrict__ xb, const __bf16* __restrict__ Wt,
    const int* __restrict__ ssrc, const int* __restrict__ sgslot,
    char* __restrict__ partials) {
  __shared__ __bf16 xs[GTM * LDS_STRIDE];  // 33792 B
  __shared__ uint2 stg[GTM][34];           // 64 rows x 256B (+16B pad) = 17408 B
  __shared__ int s_src[GTM], s_gsl[GTM];
  const int t = threadIdx.x;
  const int k = blockIdx.y;
  const int slot0 = blockIdx.x * GTM;

  if (t < GTM) {
    int sl = slot0 + t;
    s_src[t] = (sl < N_IN) ? ssrc[k * N_IN + sl] : -1;
    s_gsl[t] = (sl < N_IN) ? sgslot[k * N_IN + sl] : -1;
  }
  __syncthreads();

  // gather: 32-thread group loads one row's 512B contiguously; 16 rows/pass
  #pragma unroll
  for (int ii = 0; ii < 4; ++ii) {
    int r = ii * 16 + (t >> 5);
    int off = t & 31;             // 16B piece
    int src = s_src[r];
    uint4 v = {0u, 0u, 0u, 0u};
    if (src >= 0) v = *(const uint4*)((const char*)xb + (size_t)src * 512 + off * 16);
    *(uint4*)&xs[r * LDS_STRIDE + off * 8] = v;
  }
  __syncthreads();

  const int w = t >> 6, l = t & 63, lr = l & 15, lg = l >> 4;
  const int m  = w >> 1;   // voxel quarter (16 rows)
  const int nh = w & 1;    // channel half (64 chans)

  f32x4_t accT[4];
  #pragma unroll
  for (int n = 0; n < 4; ++n) accT[n] = (f32x4_t){0.f, 0.f, 0.f, 0.f};

  const __bf16* Wk = Wt + (size_t)k * OUTC * INC;

  #pragma unroll
  for (int s = 0; s < 8; ++s) {
    bf16x8_t a = *(const bf16x8_t*)&xs[(m * 16 + lr) * LDS_STRIDE + s * 32 + lg * 8];
    #pragma unroll
    for (int n = 0; n < 4; ++n) {
      bf16x8_t b = *(const bf16x8_t*)&Wk[((nh * 4 + n) * 16 + lr) * INC + s * 32 + lg * 8];
      accT[n] = __builtin_amdgcn_mfma_f32_16x16x32_bf16(b, a, accT[n], 0, 0, 0);
    }
  }

  // stage: lane holds voxel m*16+lr, chans (nh*4+n)*16 + lg*4 + {0..3}
  #pragma unroll
  for (int n = 0; n < 4; ++n) {
    uint2 pk;
    pk.x = pack2bf(accT[n][0], accT[n][1]);
    pk.y = pack2bf(accT[n][2], accT[n][3]);
    stg[m * 16 + lr][(nh * 4 + n) * 4 + lg] = pk;
  }
  __syncthreads();

  // store: 8 threads per row write its 256B to partials[gslot]
  {
    int r = t >> 3, p = t & 7;
    int gs = s_gsl[r];
    if (gs >= 0) {
      const uint4* rp = (const uint4*)&stg[r][0];
      char* dst = partials + (size_t)gs * 256 + p * 32;
      *(uint4*)(dst)      = rp[p * 2];
      *(uint4*)(dst + 16) = rp[p * 2 + 1];
    }
  }
}

// ============== segmented reduce + fused BN stats ==============

__global__ __launch_bounds__(256) void reduce_stats_kernel(
    const char* __restrict__ partials, const int* __restrict__ goffs,
    char* __restrict__ accb, float* __restrict__ stats) {
  const int t = threadIdx.x;
  const int lane16 = t & 15;
  const int grp = t >> 4;
  float s[8], q[8];
  #pragma unroll
  for (int i = 0; i < 8; ++i) { s[i] = 0.f; q[i] = 0.f; }

  for (int d = blockIdx.x * 16 + grp; d < N_OUT; d += gridDim.x * 16) {
    int j0 = goffs[d], j1 = goffs[d + 1];
    float a[8];
    #pragma unroll
    for (int i = 0; i < 8; ++i) a[i] = 0.f;
    for (int j = j0; j < j1; ++j) {
      uint4 v = *(const uint4*)(partials + (size_t)j * 256 + lane16 * 16);
      a[0] += bflo(v.x); a[1] += bfhi(v.x);
      a[2] += bflo(v.y); a[3] += bfhi(v.y);
      a[4] += bflo(v.z); a[5] += bfhi(v.z);
      a[6] += bflo(v.w); a[7] += bfhi(v.w);
    }
    uint4 o;
    o.x = pack2bf(a[0], a[1]); o.y = pack2bf(a[2], a[3]);
    o.z = pack2bf(a[4], a[5]); o.w = pack2bf(a[6], a[7]);
    *(uint4*)(accb + (size_t)d * 512 + lane16 * 16) = o;
    uint32_t wd[4] = {o.x, o.y, o.z, o.w};
    #pragma unroll
    for (int u = 0; u < 4; ++u) {
      float f0 = bflo(wd[u]), f1 = bfhi(wd[u]);
      s[2 * u] += f0;     q[2 * u] += f0 * f0;
      s[2 * u + 1] += f1; q[2 * u + 1] += f1 * f1;
    }
  }

  __shared__ float reds[16][16][8];
  __shared__ float redq[16][16][8];
  #pragma unroll
  for (int i = 0; i < 8; ++i) { reds[grp][lane16][i] = s[i]; redq[grp][lane16][i] = q[i]; }
  __syncthreads();
  if (t < 128) {
    float acc = 0.f;
    #pragma unroll
    for (int g2 = 0; g2 < 16; ++g2) acc += reds[g2][t >> 3][t & 7];
    atomicAdd(&stats[t], acc);
  } else {
    int c = t - 128;
    float acc = 0.f;
    #pragma unroll
    for (int g2 = 0; g2 < 16; ++g2) acc += redq[g2][c >> 3][c & 7];
    atomicAdd(&stats[128 + c], acc);
  }
}

// Read bf16 accum from row slot, write normalized fp32 over the full slot.
__global__ void norm_kernel(char* __restrict__ outb, const float* __restrict__ stats,
                            const float* __restrict__ gamma, const float* __restrict__ beta) {
  const int t = threadIdx.x;
  const int j = t & 15;
  const int ro = t >> 4;
  const float inv_n = 1.0f / (float)N_OUT;
  float sc[8], sh[8];
  #pragma unroll
  for (int i = 0; i < 8; ++i) {
    int c = j * 8 + i;
    float mean = stats[c] * inv_n;
    float var  = stats[128 + c] * inv_n - mean * mean;
    float s = gamma[c] * rsqrtf(var + BN_EPS);
    sc[i] = s;
    sh[i] = beta[c] - mean * s;
  }
  for (int r = blockIdx.x * 16 + ro; r < N_OUT; r += gridDim.x * 16) {
    uint4 v = *(const uint4*)(outb + (size_t)r * 512 + j * 16);
    uint32_t wds[4] = {v.x, v.y, v.z, v.w};
    f32x4_t o0, o1;
    #pragma unroll
    for (int u = 0; u < 4; ++u) {
      float f0 = bflo(wds[u]) * sc[2 * u] + sh[2 * u];
      float f1 = bfhi(wds[u]) * sc[2 * u + 1] + sh[2 * u + 1];
      if (u < 2) { o0[2 * u] = f0; o0[2 * u + 1] = f1; }
      else       { o1[2 * (u - 2)] = f0; o1[2 * (u - 2) + 1] = f1; }
    }
    *(f32x4_t*)(outb + (size_t)r * 512 + j * 32) = o0;
    *(f32x4_t*)(outb + (size_t)r * 512 + j * 32 + 16) = o1;
  }
}

// ======================= fallback (round-2 proven atomic path) =======================

__global__ __launch_bounds__(512, 1) void gemm_scatter_f32_kernel(
    const float* __restrict__ x, const __bf16* __restrict__ Wt,
    const int* __restrict__ out_idx, float* __restrict__ acc) {
  __shared__ __bf16 xs[GTM * LDS_STRIDE];
  const int t = threadIdx.x;
  const int row0 = blockIdx.x * GTM;
  #pragma unroll
  for (int i = 0; i < 8; ++i) {
    int f = t + i * 512;
    int r = f >> 6;
    int c4 = f & 63;
    int grow = row0 + r;
    float4 v = make_float4(0.f, 0.f, 0.f, 0.f);
    if (grow < N_IN) v = ((const float4*)x)[(size_t)grow * 64 + c4];
    bf16x4_t bv;
    bv[0] = f2bf(v.x); bv[1] = f2bf(v.y); bv[2] = f2bf(v.z); bv[3] = f2bf(v.w);
    *(bf16x4_t*)&xs[r * LDS_STRIDE + c4 * 4] = bv;
  }
  __syncthreads();
  const int w = t >> 6, l = t & 63, lr = l & 15, lg = l >> 4;
  f32x4_t accr[4][8];
  #pragma unroll
  for (int m = 0; m < 4; ++m)
    #pragma unroll
    for (int n = 0; n < 8; ++n)
      accr[m][n] = (f32x4_t){0.f, 0.f, 0.f, 0.f};
  const __bf16* Wk = Wt + (size_t)w * OUTC * INC;
  #pragma unroll
  for (int s = 0; s < 8; ++s) {
    bf16x8_t a[4], b[8];
    #pragma unroll
    for (int m = 0; m < 4; ++m)
      a[m] = *(const bf16x8_t*)&xs[(m * 16 + lr) * LDS_STRIDE + s * 32 + lg * 8];
    #pragma unroll
    for (int n = 0; n < 8; ++n)
      b[n] = *(const bf16x8_t*)&Wk[(n * 16 + lr) * INC + s * 32 + lg * 8];
    #pragma unroll
    for (int m = 0; m < 4; ++m)
      #pragma unroll
      for (int n = 0; n < 8; ++n)
        accr[m][n] = __builtin_amdgcn_mfma_f32_16x16x32_bf16(a[m], b[n], accr[m][n], 0, 0, 0);
  }
  const int* oidx = out_idx + (size_t)w * N_IN;
  #pragma unroll
  for (int m = 0; m < 4; ++m) {
    int rbase = m * 16 + lg * 4;
    #pragma unroll
    for (int reg = 0; reg < 4; ++reg) {
      int grow = row0 + rbase + reg;
      if (grow < N_IN) {
        int dst = oidx[grow];
        float* ap = acc + (size_t)dst * OUTC;
        #pragma unroll
        for (int n = 0; n < 8; ++n)
          atomicAdd(&ap[n * 16 + lr], accr[m][n][reg]);
      }
    }
  }
}

__global__ void stats_f32_kernel(const float* __restrict__ acc, float* __restrict__ stats) {
  const int t = threadIdx.x;
  const int c4 = t & 31;
  const int ro = t >> 5;
  f32x4_t s = {0.f, 0.f, 0.f, 0.f}, q = {0.f, 0.f, 0.f, 0.f};
  for (int r = blockIdx.x * 8 + ro; r < N_OUT; r += gridDim.x * 8) {
    f32x4_t v = ((const f32x4_t*)acc)[(size_t)r * 32 + c4];
    s += v; q += v * v;
  }
  __shared__ float red[256][8];
  #pragma unroll
  for (int j = 0; j < 4; ++j) { red[t][j] = s[j]; red[t][4 + j] = q[j]; }
  __syncthreads();
  if (t < 32) {
    float S[4] = {0.f, 0.f, 0.f, 0.f}, Q[4] = {0.f, 0.f, 0.f, 0.f};
    for (int r2 = 0; r2 < 8; ++r2)
      #pragma unroll
      for (int j = 0; j < 4; ++j) {
        S[j] += red[r2 * 32 + t][j];
        Q[j] += red[r2 * 32 + t][4 + j];
      }
    #pragma unroll
    for (int j = 0; j < 4; ++j) {
      atomicAdd(&stats[t * 4 + j], S[j]);
      atomicAdd(&stats[128 + t * 4 + j], Q[j]);
    }
  }
}

__global__ void norm_f32_kernel(float* __restrict__ out, const float* __restrict__ stats,
                                const float* __restrict__ gamma, const float* __restrict__ beta) {
  const int t = threadIdx.x;
  const int c4 = t & 31;
  const int ro = t >> 5;
  const float inv_n = 1.0f / (float)N_OUT;
  float sc[4], sh[4];
  #pragma unroll
  for (int j = 0; j < 4; ++j) {
    int c = c4 * 4 + j;
    float mean = stats[c] * inv_n;
    float var  = stats[128 + c] * inv_n - mean * mean;
    float s = gamma[c] * rsqrtf(var + BN_EPS);
    sc[j] = s;
    sh[j] = beta[c] - mean * s;
  }
  for (int r = blockIdx.x * 8 + ro; r < N_OUT; r += gridDim.x * 8) {
    f32x4_t v = ((const f32x4_t*)out)[(size_t)r * 32 + c4];
    #pragma unroll
    for (int j = 0; j < 4; ++j) v[j] = v[j] * sc[j] + sh[j];
    ((f32x4_t*)out)[(size_t)r * 32 + c4] = v;
  }
}

// ======================= launch =======================

extern "C" void kernel_launch(void* const* d_in, const int* in_sizes, int n_in,
                              void* d_out, int out_size, void* d_ws, size_t ws_size,
                              hipStream_t stream) {
  const float* x     = (const float*)d_in[0];
  const float* W     = (const float*)d_in[1];
  const float* gamma = (const float*)d_in[2];
  const float* beta  = (const float*)d_in[3];
  const int*   oidx  = (const int*)d_in[4];

  // ws layout: partials + goffs + stats  (needs 514 MB; 526.5 MB proven available)
  const size_t PART_OFF  = 0;                  // 512,000,000
  const size_t GOFFS_OFF = 512000000;          // (500001 ints) 2,000,004 -> pad
  const size_t STATS_OFF = 514000016;          // 1,024
  const size_t NEED      = 514001040;

  if (ws_size >= NEED) {
    char* ws = (char*)d_ws;
    char* partials = ws + PART_OFF;
    int* goffs  = (int*)(ws + GOFFS_OFF);
    float* stats = (float*)(ws + STATS_OFF);

    // transient scratch inside d_out (dead before reduce overwrites it)
    char* ob = (char*)d_out;
    uint32_t* xb   = (uint32_t*)(ob);                 // 128,000,000  x_bf16
    int* cnt8      = (int*)(ob + 128000000);          // 16,000,000
    int* cur8      = (int*)(ob + 144000000);          // 16,000,000
    int* gcnt      = (int*)(ob + 160000000);          //  2,000,000
    int* gcur      = (int*)(ob + 162000000);          //  2,000,016 (pad)
    int* ssrc      = (int*)(ob + 164000016);          //  8,000,000
    int* sgslot    = (int*)(ob + 172000016);          //  8,000,000
    __bf16* Wt     = (__bf16*)(ob + 180000016);       //    524,288
    int* bsum8     = (int*)(ob + 180524304);          // 8*489*4 = 15,648
    int* bsumx8    = (int*)(ob + 180539952);          //     15,648
    int* gbsum     = (int*)(ob + 180555600);          //      1,968 (pad)
    int* gbsumx    = (int*)(ob + 180557568);          //      1,968

    hipMemsetAsync(cnt8, 0, (size_t)KVOL * N_OUT * sizeof(int), stream);
    hipMemsetAsync(gcnt, 0, (size_t)N_OUT * sizeof(int), stream);
    hipMemsetAsync(stats, 0, 256 * sizeof(float), stream);

    xconv_kernel<<<(N_IN * INC / 8 + 255) / 256, 256, 0, stream>>>(x, xb);
    wconv_kernel<<<(KVOL * OUTC * INC + 255) / 256, 256, 0, stream>>>(W, Wt);
    hist8_kernel<<<dim3((N_IN + 255) / 256, KVOL), 256, 0, stream>>>(oidx, cnt8, gcnt);
    // per-k scans -> cur8
    scan1s_kernel<<<dim3(DCHUNKS, KVOL), 256, 0, stream>>>(cnt8, cur8, bsum8);
    scan2s_kernel<<<KVOL, 512, 0, stream>>>(bsum8, bsumx8);
    scan3s_kernel<<<dim3((N_OUT + 255) / 256, KVOL), 256, 0, stream>>>(cur8, bsumx8);
    // global scan -> goffs (ws) + gcur
    scan1s_kernel<<<dim3(DCHUNKS, 1), 256, 0, stream>>>(gcnt, goffs, gbsum);
    scan2s_kernel<<<1, 512, 0, stream>>>(gbsum, gbsumx);
    scan3g_kernel<<<(N_OUT + 255) / 256, 256, 0, stream>>>(goffs, gcur, gbsumx);
    fill_kernel<<<dim3((N_IN + 255) / 256, KVOL), 256, 0, stream>>>(
        oidx, cur8, gcur, ssrc, sgslot);
    gemm_gather_store_kernel<<<dim3((N_IN + GTM - 1) / GTM, KVOL), 512, 0, stream>>>(
        xb, Wt, ssrc, sgslot, partials);
    reduce_stats_kernel<<<2048, 256, 0, stream>>>(partials, goffs, ob, stats);
    norm_kernel<<<1024, 256, 0, stream>>>(ob, stats, gamma, beta);
  } else {
    // fallback: proven round-2 atomic pipeline (needs only ~526 KB ws)
    __bf16* Wt   = (__bf16*)d_ws;
    float* stats = (float*)((char*)d_ws + (size_t)KVOL * OUTC * INC * 2);
    float* out = (float*)d_out;

    hipMemsetAsync(d_out, 0, (size_t)N_OUT * OUTC * sizeof(float), stream);
    hipMemsetAsync(stats, 0, 256 * sizeof(float), stream);

    wconv_kernel<<<(KVOL * OUTC * INC + 255) / 256, 256, 0, stream>>>(W, Wt);
    gemm_scatter_f32_kernel<<<(N_IN + GTM - 1) / GTM, 512, 0, stream>>>(x, Wt, oidx, out);
    stats_f32_kernel<<<1024, 256, 0, stream>>>(out, stats);
    norm_f32_kernel<<<2048, 256, 0, stream>>>(out, stats, gamma, beta);
  }
}